// Round 8
// baseline (177.586 us; speedup 1.0000x reference)
//
#include <hip/hip_runtime.h>

#define HEADS  16
#define DH     64
#define SEQ    2048
#define NBATCH 2
#define EMB    1024
#define MTOT   (NBATCH * SEQ)  // 4096

// Q pre-scale: 1/sqrt(1024) * log2(e)  (softmax done in base 2, fixed-max)
#define QSCALE 0.045084220027780106f

typedef short  s16x8 __attribute__((ext_vector_type(8)));
typedef float  f32x4 __attribute__((ext_vector_type(4)));
typedef unsigned short u16;
typedef unsigned short u16x4 __attribute__((ext_vector_type(4)));

__device__ __forceinline__ u16 f2bf(float f) {
  unsigned u = __builtin_bit_cast(unsigned, f);
  u += 0x7fffu + ((u >> 16) & 1u);   // RNE
  return (u16)(u >> 16);
}

// async global->LDS, 16B per lane; lds ptr wave-uniform base (HW adds lane*16)
__device__ __forceinline__ void gll16(const u16* g, u16* l) {
  __builtin_amdgcn_global_load_lds(
      (const __attribute__((address_space(1))) unsigned int*)g,
      (__attribute__((address_space(3))) unsigned int*)l, 16, 0, 0);
}

// ---------------- fused conversions: one launch ----------------
// z in 0..3: weight transpose+convert Wt[n][k] = bf16(W[k][n]) (32x32 tile per block)
// z == 4:    fp32 -> bf16 bulk convert of x (1024 blocks x 256 thr x 16 floats)
__global__ void cvt_fused(const float* __restrict__ x, u16* __restrict__ xb,
                          const float* __restrict__ Wq, const float* __restrict__ Wk,
                          const float* __restrict__ Wv, const float* __restrict__ Wo,
                          u16* __restrict__ Wqt, u16* __restrict__ Wkt,
                          u16* __restrict__ Wvt, u16* __restrict__ Wot) {
  int tx = threadIdx.x, ty = threadIdx.y;
  if (blockIdx.z == 4) {
    int tid = ty * 32 + tx;
    int base = (blockIdx.y * 32 + blockIdx.x) * 4096;   // 1024 blocks x 4096 floats
#pragma unroll
    for (int j = 0; j < 4; j++) {
      int i = base + j * 1024 + tid * 4;
      float4 v = *(const float4*)(x + i);
      u16x4 o;
      o.x = f2bf(v.x); o.y = f2bf(v.y); o.z = f2bf(v.z); o.w = f2bf(v.w);
      *(u16x4*)(xb + i) = o;
    }
    return;
  }
  __shared__ float tile[32][33];
  const float* W; u16* T;
  switch (blockIdx.z) {
    case 0:  W = Wq; T = Wqt; break;
    case 1:  W = Wk; T = Wkt; break;
    case 2:  W = Wv; T = Wvt; break;
    default: W = Wo; T = Wot; break;
  }
  int n0 = blockIdx.x * 32, k0 = blockIdx.y * 32;
#pragma unroll
  for (int r = 0; r < 32; r += 8)
    tile[ty + r][tx] = W[(size_t)(k0 + ty + r) * EMB + n0 + tx];
  __syncthreads();
#pragma unroll
  for (int r = 0; r < 32; r += 8)
    T[(size_t)(n0 + ty + r) * EMB + k0 + tx] = f2bf(tile[tx][ty + r]);
}

// ---------------- GEMM mainloop: BM=128, BN=64, BK=64, 256 thr / 4 waves (2x2) ----------
// BN=64 / 24KB LDS: 6 blocks/CU co-resident (grid 1536 = 6/CU) -- at K=1024 (16 K-steps)
// cross-block TLP hides the per-step barrier drain better than any per-block pipeline
// tried (BN=128: 56us; drain-0 dbuf: 44.2; 256^2 counted-vmcnt coarse: 45.3; 256^2
// m201 4-phase: 45.5 -- qkv time is structure-invariant at ~44, this 1-phase is best).
// LDS layout XOR-swizzled: physical 16B-chunk p of row holds logical chunk (p&7)^(row&7).
__device__ __forceinline__ void gemm_core(const u16* __restrict__ A, const u16* __restrict__ Bt,
                                          u16* As, u16* Bs, int m0, int n0, f32x4 acc[4][2]) {
  const int tid = threadIdx.x;
  const int lane = tid & 63, w = tid >> 6;
  const int wm = w >> 1, wn = w & 1;
  const int lr = lane & 15, lq = lane >> 4;
#pragma unroll
  for (int i = 0; i < 4; i++)
#pragma unroll
    for (int j = 0; j < 2; j++)
      acc[i][j] = (f32x4){0.f, 0.f, 0.f, 0.f};

  for (int k0 = 0; k0 < EMB; k0 += 64) {
    __syncthreads();
#pragma unroll
    for (int j = 0; j < 4; j++) {
      int c = tid + 256 * j;
      int row = c >> 3, c8 = (c & 7) ^ (row & 7);
      gll16(&A[(size_t)(m0 + row) * EMB + k0 + c8 * 8],
            &As[(w * 64 + 256 * j) * 8]);
    }
#pragma unroll
    for (int j = 0; j < 2; j++) {
      int c = tid + 256 * j;
      int row = c >> 3, c8 = (c & 7) ^ (row & 7);
      gll16(&Bt[(size_t)(n0 + row) * EMB + k0 + c8 * 8],
            &Bs[(w * 64 + 256 * j) * 8]);
    }
    __syncthreads();
#pragma unroll
    for (int kk8 = 0; kk8 < 8; kk8 += 4) {
      s16x8 af[4], bf[2];
#pragma unroll
      for (int i = 0; i < 4; i++) {
        int row = wm * 64 + i * 16 + lr;
        af[i] = *(const s16x8*)&As[row * 64 + (((kk8 + lq) ^ (row & 7)) * 8)];
      }
#pragma unroll
      for (int j = 0; j < 2; j++) {
        int row = wn * 32 + j * 16 + lr;
        bf[j] = *(const s16x8*)&Bs[row * 64 + (((kk8 + lq) ^ (row & 7)) * 8)];
      }
#pragma unroll
      for (int i = 0; i < 4; i++)
#pragma unroll
        for (int j = 0; j < 2; j++)
          acc[i][j] = __builtin_amdgcn_mfma_f32_16x16x32_bf16(af[i], bf[j], acc[i][j], 0, 0, 0);
    }
  }
}

// QKV fused: mode selects {Wq->Qb (scaled), Wk->Kb, Wv->Vtb (transposed)}
// XCD-clustered job remap (1536 = 8*192): A row-panel L2-shared within an XCD.
__global__ __launch_bounds__(256) void gemm_qkv(const u16* __restrict__ xb,
                                                const u16* __restrict__ Wqt, const u16* __restrict__ Wkt,
                                                const u16* __restrict__ Wvt,
                                                const float* __restrict__ bq, const float* __restrict__ bk,
                                                const float* __restrict__ bv,
                                                u16* __restrict__ Qb, u16* __restrict__ Kb,
                                                u16* __restrict__ Vtb) {
  __shared__ __align__(16) u16 As[128 * 64];
  __shared__ __align__(16) u16 Bs[64 * 64];
  const int lin  = blockIdx.x + 16 * (blockIdx.y + 32 * blockIdx.z);
  const int job  = (lin & 7) * 192 + (lin >> 3);   // bijective: 1536 = 8*192
  const int mode = job >> 9;                        // 512 jobs per mode
  const int rem  = job & 511;
  const int m0 = (rem >> 4) * 128, n0 = (rem & 15) * 64;

  const u16* Bt; const float* bias; u16* out;
  switch (mode) {
    case 0:  Bt = Wqt; bias = bq; out = Qb;  break;
    case 1:  Bt = Wkt; bias = bk; out = Kb;  break;
    default: Bt = Wvt; bias = bv; out = Vtb; break;
  }
  f32x4 acc[4][2];
  gemm_core(xb, Bt, As, Bs, m0, n0, acc);

  const int tid = threadIdx.x, lane = tid & 63, w = tid >> 6;
  const int wm = w >> 1, wn = w & 1;
  const int lr = lane & 15, lq = lane >> 4;
#pragma unroll
  for (int i = 0; i < 4; i++) {
#pragma unroll
    for (int j = 0; j < 2; j++) {
      int col   = n0 + wn * 32 + j * 16 + lr;
      int mbase = m0 + wm * 64 + i * 16 + lq * 4;
      float bv_ = bias[col];
      int h = col >> 6, d = col & 63;
      if (mode == 0) {
#pragma unroll
        for (int r = 0; r < 4; r++) {
          int m = mbase + r, b = m >> 11, s = m & (SEQ - 1);
          out[((size_t)(b * HEADS + h) * SEQ + s) * DH + d] = f2bf((acc[i][j][r] + bv_) * QSCALE);
        }
      } else if (mode == 1) {
#pragma unroll
        for (int r = 0; r < 4; r++) {
          int m = mbase + r, b = m >> 11, s = m & (SEQ - 1);
          out[((size_t)(b * HEADS + h) * SEQ + s) * DH + d] = f2bf(acc[i][j][r] + bv_);
        }
      } else {
        int b = mbase >> 11, s = mbase & (SEQ - 1);
        u16x4 pk;
        pk.x = f2bf(acc[i][j][0] + bv_);
        pk.y = f2bf(acc[i][j][1] + bv_);
        pk.z = f2bf(acc[i][j][2] + bv_);
        pk.w = f2bf(acc[i][j][3] + bv_);
        *(u16x4*)&out[((size_t)(b * HEADS + h) * DH + d) * SEQ + s] = pk;
      }
    }
  }
}

// output projection: fp32 out, BM=128, BN=64; XCD-clustered remap (512 = 8*64)
__global__ __launch_bounds__(256) void gemm_out(const u16* __restrict__ A, const u16* __restrict__ Bt,
                                                const float* __restrict__ bias, float* __restrict__ out) {
  __shared__ __align__(16) u16 As[128 * 64];
  __shared__ __align__(16) u16 Bs[64 * 64];
  const int lin = blockIdx.x + 16 * blockIdx.y;
  const int job = (lin & 7) * 64 + (lin >> 3);     // bijective: 512 = 8*64
  const int m0 = (job >> 4) * 128, n0 = (job & 15) * 64;
  f32x4 acc[4][2];
  gemm_core(A, Bt, As, Bs, m0, n0, acc);

  const int tid = threadIdx.x, lane = tid & 63, w = tid >> 6;
  const int wm = w >> 1, wn = w & 1;
  const int lr = lane & 15, lq = lane >> 4;
#pragma unroll
  for (int i = 0; i < 4; i++) {
#pragma unroll
    for (int j = 0; j < 2; j++) {
      int col   = n0 + wn * 32 + j * 16 + lr;
      int mbase = m0 + wm * 64 + i * 16 + lq * 4;
      float bv_ = bias[col];
#pragma unroll
      for (int r = 0; r < 4; r++)
        out[(size_t)(mbase + r) * EMB + col] = acc[i][j][r] + bv_;
    }
  }
}

// ---------------- fused causal attention: 128-row q-tiles, 32 q-rows per wave ----------
// LDS-throughput analysis (R0 counters): old 16-row waves moved 192 KB LDS/block-iter =
// ~73% of the 85 B/cyc/CU ds_read_b128 ceiling -> LDS-BW-bound. Every wave reads the
// full 64x64 K and V tiles, so q-rows/wave is the reuse knob: 32-row waves read K/V
// fragments ONCE per t and use them for both 16-row sub-blocks (qb=0,1).
// Per wave-iter: 28 LDS ops / 32 MFMA for 2x the work -> LDS bytes per work /1.8;
// staged global traffic per work halves too.
// Geometry: q-tile = 128 rows (4 waves x 32); pairing (pA=px, pB=15-px) gives EXACTLY
// 17 uniform iters per group, zero padding: group0 = 2px+2 A-jobs + (15-2px) B-prefix;
// group1 = 17 B-suffix (j = 15-2px+i). Grid (8,32) = 256 blocks = 1/CU, 8 waves/CU.
// Masks generalized: apply when 64j+63 > qmin(wave,qb); lane test gk > gq.
// XCD remap (256 = 8*32): each XCD owns 4 complete heads (K+V = 2 MB < 4 MB L2).
__global__ __launch_bounds__(512, 2) void attn_fwd(const u16* __restrict__ Q,
                                                   const u16* __restrict__ Kg,
                                                   const u16* __restrict__ Vt,
                                                   u16* __restrict__ O) {
  // carve (u16): KsA=0 (5120), VsA=5120 (5120), KsB=10240, VsB=15360, pw=20480 (8x2560)
  __shared__ __align__(16) u16 smem[40960];
  const int tid = threadIdx.x, lane = tid & 63, w = tid >> 6;
  const int g = w >> 2, wg = w & 3;
  const int lr = lane & 15, lq = lane >> 4;
  const int lin = blockIdx.x + 8 * blockIdx.y;
  const int job = (lin & 7) * 32 + (lin >> 3);     // bijective: 256 = 8*32
  const int px = job & 7, bh = job >> 3;
  const int pB = 15 - px;
  const int qoff = wg * 32;
  const int trans = 2 * px + 2;                    // group-0 A->B transition iter
  u16* Ks = smem + (g ? 10240 : 0);
  u16* Vs = smem + (g ? 15360 : 5120);
  u16* pw = smem + 20480 + w * 2560;               // [32 q][80] per wave
  const size_t qkbase = (size_t)bh * SEQ * DH;
  const size_t vbase  = (size_t)bh * DH * SEQ;
  const u16* kgp = Kg + qkbase;
  const u16* vtp = Vt + vbase;
  const int t256 = tid & 255;
  const int b = bh >> 4, hh = bh & 15;

  // Q frags [qb][chunk]; group 0 starts on tile A (px), group 1 on tile B (pB)
  s16x8 qf[2][2];
  int qbase = (g ? pB : px) * 128;
  {
    const u16* qp = Q + qkbase + (size_t)(qbase + qoff + lr) * DH;
    qf[0][0] = *(const s16x8*)&qp[lq * 8];
    qf[0][1] = *(const s16x8*)&qp[32 + lq * 8];
    qf[1][0] = *(const s16x8*)&qp[16 * DH + lq * 8];
    qf[1][1] = *(const s16x8*)&qp[16 * DH + 32 + lq * 8];
  }
  f32x4 o[2][4];
  float psum[2] = {0.f, 0.f};
#pragma unroll
  for (int qb = 0; qb < 2; qb++)
#pragma unroll
    for (int t = 0; t < 4; t++) o[qb][t] = (f32x4){0.f, 0.f, 0.f, 0.f};

  // staging: 256 thr/group, 2x16B K-chunks + 2x16B V-chunks each
  const int srow = t256 >> 3, soff = (t256 & 7) * 8;
  int kt0 = g ? (15 - 2 * px) : 0;
  s16x8 kr0 = *(const s16x8*)&kgp[(size_t)(kt0 * 64 + srow) * DH + soff];
  s16x8 kr1 = *(const s16x8*)&kgp[(size_t)(kt0 * 64 + srow + 32) * DH + soff];
  s16x8 vr0 = *(const s16x8*)&vtp[(size_t)srow * SEQ + kt0 * 64 + soff];
  s16x8 vr1 = *(const s16x8*)&vtp[(size_t)(srow + 32) * SEQ + kt0 * 64 + soff];

  for (int i = 0; i < 17; ++i) {
    __syncthreads();   // previous iteration's LDS readers done
    *(s16x8*)&Ks[srow * 80 + soff]        = kr0;
    *(s16x8*)&Ks[(srow + 32) * 80 + soff] = kr1;
    *(s16x8*)&Vs[srow * 80 + soff]        = vr0;
    *(s16x8*)&Vs[(srow + 32) * 80 + soff] = vr1;
    __syncthreads();

    // register prefetch of next tile (overlaps compute)
    if (i + 1 < 17) {
      int ktn = g ? (16 - 2 * px + i)
                  : ((i + 1 < trans) ? (i + 1) : (i + 1 - trans));
      kr0 = *(const s16x8*)&kgp[(size_t)(ktn * 64 + srow) * DH + soff];
      kr1 = *(const s16x8*)&kgp[(size_t)(ktn * 64 + srow + 32) * DH + soff];
      vr0 = *(const s16x8*)&vtp[(size_t)srow * SEQ + ktn * 64 + soff];
      vr1 = *(const s16x8*)&vtp[(size_t)(srow + 32) * SEQ + ktn * 64 + soff];
    }

    // group-0 phase transition: tile A complete -> write it, reset acc, switch Q to B
    if (g == 0 && i == trans) {
#pragma unroll
      for (int qb = 0; qb < 2; qb++) {
        float s2 = psum[qb] + __shfl_xor(psum[qb], 16);
        float s4 = s2 + __shfl_xor(s2, 32);
        float inv[4];
#pragma unroll
        for (int r = 0; r < 4; r++) inv[r] = __builtin_amdgcn_rcpf(__shfl(s4, lq * 4 + r));
#pragma unroll
        for (int t = 0; t < 4; t++)
#pragma unroll
          for (int r = 0; r < 4; r++) {
            int m = b * SEQ + px * 128 + qoff + qb * 16 + lq * 4 + r;
            O[(size_t)m * EMB + hh * 64 + t * 16 + lr] = f2bf(o[qb][t][r] * inv[r]);
          }
#pragma unroll
        for (int t = 0; t < 4; t++) o[qb][t] = (f32x4){0.f, 0.f, 0.f, 0.f};
        psum[qb] = 0.f;
      }
      qbase = pB * 128;
      const u16* qp = Q + qkbase + (size_t)(qbase + qoff + lr) * DH;
      qf[0][0] = *(const s16x8*)&qp[lq * 8];
      qf[0][1] = *(const s16x8*)&qp[32 + lq * 8];
      qf[1][0] = *(const s16x8*)&qp[16 * DH + lq * 8];
      qf[1][1] = *(const s16x8*)&qp[16 * DH + 32 + lq * 8];
    }

    const int j = g ? (15 - 2 * px + i) : ((i < trans) ? i : (i - trans));

    // S^T = K @ Q^T, both q-sub-blocks sharing each K fragment (8 K-reads serve 16 MFMA)
    f32x4 sc[2][4];
    __builtin_amdgcn_s_setprio(1);
#pragma unroll
    for (int t = 0; t < 4; t++) {
      s16x8 kf0 = *(const s16x8*)&Ks[(t * 16 + lr) * 80 + lq * 8];
      s16x8 kf1 = *(const s16x8*)&Ks[(t * 16 + lr) * 80 + 32 + lq * 8];
#pragma unroll
      for (int qb = 0; qb < 2; qb++) {
        f32x4 z = (f32x4){0.f, 0.f, 0.f, 0.f};
        z = __builtin_amdgcn_mfma_f32_16x16x32_bf16(kf0, qf[qb][0], z, 0, 0, 0);
        z = __builtin_amdgcn_mfma_f32_16x16x32_bf16(kf1, qf[qb][1], z, 0, 0, 0);
        sc[qb][t] = z;   // sc[qb][t][r] = S[k = 64j + t*16+lq*4+r][q = qbase+qoff+qb*16+lr]
      }
    }
    __builtin_amdgcn_s_setprio(0);

    // causal mask (arithmetic form): only active near/above the diagonal
#pragma unroll
    for (int qb = 0; qb < 2; qb++) {
      int qmin = qbase + qoff + qb * 16;
      if (64 * j + 63 > qmin) {
        int gq = qmin + lr;
#pragma unroll
        for (int t = 0; t < 4; t++)
#pragma unroll
          for (int r = 0; r < 4; r++)
            if (64 * j + t * 16 + lq * 4 + r > gq) sc[qb][t][r] = -1e9f;
      }
    }

    // exp2 + denominator accumulate + packed P-write (k-contiguous 8B stores)
#pragma unroll
    for (int qb = 0; qb < 2; qb++)
#pragma unroll
      for (int t = 0; t < 4; t++) {
        u16x4 pk;
#pragma unroll
        for (int r = 0; r < 4; r++) {
          float p = __builtin_amdgcn_exp2f(sc[qb][t][r]);
          psum[qb] += p;
          pk[r] = f2bf(p);
        }
        *(u16x4*)&pw[(qb * 16 + lr) * 80 + t * 16 + lq * 4] = pk;
      }

    // O += P @ V : 8 V-reads serve 16 MFMA (both qb)
    __builtin_amdgcn_s_setprio(1);
#pragma unroll
    for (int kc = 0; kc < 2; kc++) {
      s16x8 pf[2];
#pragma unroll
      for (int qb = 0; qb < 2; qb++)
        pf[qb] = *(const s16x8*)&pw[(qb * 16 + lr) * 80 + kc * 32 + lq * 8];
#pragma unroll
      for (int t = 0; t < 4; t++) {
        s16x8 vf = *(const s16x8*)&Vs[(t * 16 + lr) * 80 + kc * 32 + lq * 8];
#pragma unroll
        for (int qb = 0; qb < 2; qb++)
          o[qb][t] = __builtin_amdgcn_mfma_f32_16x16x32_bf16(pf[qb], vf, o[qb][t], 0, 0, 0);
      }
    }
    __builtin_amdgcn_s_setprio(0);
  }

  // ---- combine tile B: group 0's partial (fp32) added into group 1's, then write ----
  __syncthreads();
  float* Cb = (float*)smem;             // [128][68] fp32 partials (over K/V bufs, 34.8 KB)
  float* Ss = (float*)(smem + 20480);   // 128 partial row-sums (over pw region)
  if (g == 0) {
#pragma unroll
    for (int qb = 0; qb < 2; qb++) {
      float s2 = psum[qb] + __shfl_xor(psum[qb], 16);
      float s4 = s2 + __shfl_xor(s2, 32);
      if (lq == 0) Ss[qoff + qb * 16 + lr] = s4;
#pragma unroll
      for (int t = 0; t < 4; t++)
#pragma unroll
        for (int r = 0; r < 4; r++)
          Cb[(qoff + qb * 16 + lq * 4 + r) * 68 + t * 16 + lr] = o[qb][t][r];
    }
  }
  __syncthreads();
  if (g == 1) {
#pragma unroll
    for (int qb = 0; qb < 2; qb++) {
      float s2 = psum[qb] + __shfl_xor(psum[qb], 16);
      float s4 = s2 + __shfl_xor(s2, 32);
      float inv[4];
#pragma unroll
      for (int r = 0; r < 4; r++)
        inv[r] = __builtin_amdgcn_rcpf(__shfl(s4, lq * 4 + r) + Ss[qoff + qb * 16 + lq * 4 + r]);
#pragma unroll
      for (int t = 0; t < 4; t++)
#pragma unroll
        for (int r = 0; r < 4; r++) {
          int m = b * SEQ + pB * 128 + qoff + qb * 16 + lq * 4 + r;
          float v = o[qb][t][r] + Cb[(qoff + qb * 16 + lq * 4 + r) * 68 + t * 16 + lr];
          O[(size_t)m * EMB + hh * 64 + t * 16 + lr] = f2bf(v * inv[r]);
        }
    }
  }
}

extern "C" void kernel_launch(void* const* d_in, const int* in_sizes, int n_in,
                              void* d_out, int out_size, void* d_ws, size_t ws_size,
                              hipStream_t stream) {
  const float* x  = (const float*)d_in[0];
  const float* Wq = (const float*)d_in[2];
  const float* bq = (const float*)d_in[3];
  const float* Wk = (const float*)d_in[4];
  const float* bk = (const float*)d_in[5];
  const float* Wv = (const float*)d_in[6];
  const float* bv = (const float*)d_in[7];
  const float* Wo = (const float*)d_in[8];
  const float* bo = (const float*)d_in[9];

  char* ws = (char*)d_ws;
  const size_t MB = 1024 * 1024;
  u16* Qb  = (u16*)(ws + 0 * MB);    // [B][H][S][Dh] bf16 (pre-scaled by QSCALE)
  u16* Kb  = (u16*)(ws + 8 * MB);    // [B][H][S][Dh] bf16
  u16* Vtb = (u16*)(ws + 16 * MB);   // [B][H][Dh][S] bf16
  u16* xb  = (u16*)(ws + 24 * MB);   // [M][E] bf16
  u16* Ob  = xb;                     // alias: xb dead after QKV GEMMs
  u16* Wqt = (u16*)(ws + 32 * MB);
  u16* Wkt = (u16*)(ws + 34 * MB);
  u16* Wvt = (u16*)(ws + 36 * MB);
  u16* Wot = (u16*)(ws + 38 * MB);

  cvt_fused<<<dim3(32, 32, 5), dim3(32, 8), 0, stream>>>(
      x, xb, Wq, Wk, Wv, Wo, Wqt, Wkt, Wvt, Wot);

  gemm_qkv<<<dim3(EMB / 64, MTOT / 128, 3), 256, 0, stream>>>(
      xb, Wqt, Wkt, Wvt, bq, bk, bv, Qb, Kb, Vtb);

  attn_fwd<<<dim3(8, 32), 512, 0, stream>>>(Qb, Kb, Vtb, Ob);

  gemm_out<<<dim3(EMB / 64, MTOT / 128), 256, 0, stream>>>(Ob, Wot, bo, (float*)d_out);
}